// Round 12
// baseline (52.274 us; speedup 1.0000x reference)
//
#include <hip/hip_runtime.h>

// AttentionHead: B=4, S=4096, D=64, fp32 in/out.
// R12: 64q/wave (two 32-q groups SEQUENTIALLY per iteration, sharing one
// LDS read of K/V fragments -> per-q LDS traffic and barriers halve) with
// R10's verified fp32 raw-dump epilogue (+1 group bit) and merge.
// Bisect of R11: fp16 epilogue and 4-concurrent-score-chain pressure removed.

#define BATCH 4
#define SEQ   4096
#define DIM   64
#define KVB   64
#define NQ    16384                  // BATCH*SEQ
#define QSCALE 0.18033688011112042f  // (1/sqrt(64)) * log2(e); all exps are exp2

typedef float f32x16 __attribute__((ext_vector_type(16)));
typedef unsigned short u16x8 __attribute__((ext_vector_type(8)));
typedef unsigned int   u32x4 __attribute__((ext_vector_type(4)));
typedef unsigned int   u32x2 __attribute__((ext_vector_type(2)));

#define MFMA32(a, b, c) __builtin_amdgcn_mfma_f32_32x32x16_bf16((a), (b), (c), 0, 0, 0)
#define EXP2F(x) __builtin_amdgcn_exp2f(x)

__device__ __forceinline__ void plswap(unsigned int& a, unsigned int& b) {
  u32x2 r = __builtin_amdgcn_permlane32_swap(a, b, false, false);
  a = r[0]; b = r[1];
}
__device__ __forceinline__ float xsum32(float x) {   // total across lane^32
  unsigned int u = __float_as_uint(x), v = u;
  plswap(u, v);
  return __uint_as_float(u) + __uint_as_float(v);
}

__device__ __forceinline__ unsigned short f2bf(float x) {
  unsigned int u = __float_as_uint(x);
  return (unsigned short)((u + 0x7fffu + ((u >> 16) & 1u)) >> 16);   // RNE
}
__device__ __forceinline__ unsigned int cvtpk(float a, float b) {  // lo=a, hi=b
  unsigned int r;
  asm("v_cvt_pk_bf16_f32 %0, %1, %2" : "=v"(r) : "v"(a), "v"(b));
  return r;
}

// ---------------- prep: K,V -> fragment-ordered bf16 (verified R7-R10) ------
// Kf block (b, kb32, ch): elem l*8+j = K[b][kb32*32+(l&31)][ch*16+(l>>5)*8+j]
// Vf block (b, kb64, dh, ks): elem l*8+j = V[b][kb64*64+ks*16+(l>>5)*8+j][dh*32+(l&31)]
__global__ __launch_bounds__(256) void prep_kernel(
    const float* __restrict__ K, const float* __restrict__ V,
    unsigned short* __restrict__ Kf, unsigned short* __restrict__ Vf) {
  __shared__ float tk[64][65];
  __shared__ float tv[64][65];
  const int t = threadIdx.x;
  const int b = blockIdx.x >> 6;
  const int s0 = (blockIdx.x & 63) << 6;
  #pragma unroll
  for (int r = 0; r < 4; ++r) {
    const int s_loc = r * 16 + (t >> 4);
    const int d0 = (t & 15) << 2;
    const long base = ((long)b * SEQ + s0 + s_loc) * DIM + d0;
    const float4 kv = *(const float4*)(K + base);
    const float4 vv = *(const float4*)(V + base);
    tk[s_loc][d0 + 0] = kv.x; tk[s_loc][d0 + 1] = kv.y;
    tk[s_loc][d0 + 2] = kv.z; tk[s_loc][d0 + 3] = kv.w;
    tv[s_loc][d0 + 0] = vv.x; tv[s_loc][d0 + 1] = vv.y;
    tv[s_loc][d0 + 2] = vv.z; tv[s_loc][d0 + 3] = vv.w;
  }
  __syncthreads();
  const int l  = t >> 2;           // 0..63 (fragment lane)
  const int j0 = (t & 3) << 1;     // 0,2,4,6
  const int l5 = l & 31, b5 = l >> 5;
  #pragma unroll
  for (int kh = 0; kh < 2; ++kh) {
    #pragma unroll
    for (int ch = 0; ch < 4; ++ch) {
      const int key = kh * 32 + l5;
      const int d   = ch * 16 + b5 * 8 + j0;
      ushort2 w;
      w.x = f2bf(tk[key][d]);
      w.y = f2bf(tk[key][d + 1]);
      const long kb32 = (s0 >> 5) + kh;
      const long off = (((long)b * 128 + kb32) * 4 + ch) * 512 + 2 * t;
      *(ushort2*)(Kf + off) = w;
    }
  }
  #pragma unroll
  for (int dh = 0; dh < 2; ++dh) {
    #pragma unroll
    for (int ks = 0; ks < 4; ++ks) {
      const int key0 = ks * 16 + b5 * 8 + j0;
      const int d    = dh * 32 + l5;
      ushort2 w;
      w.x = f2bf(tv[key0][d]);
      w.y = f2bf(tv[key0 + 1][d]);
      const long kb64 = (s0 >> 6);
      const long off = ((((long)b * 64 + kb64) * 2 + dh) * 4 + ks) * 512 + 2 * t;
      *(ushort2*)(Vf + off) = w;
    }
  }
}

// ---------------- attention main kernel ------------------------------------
// WG = 4 waves x 64 q (two 32-q groups, processed sequentially) = 256 q.
template<int NS>
__global__ __launch_bounds__(256, 2) void attn_kernel(
    const float* __restrict__ Q,
    const unsigned short* __restrict__ Kf, const unsigned short* __restrict__ Vf,
    float* __restrict__ Opart, float* __restrict__ Lpart) {

  // 2 bufs x 16 fragment blocks (K: 0-7, V: 8-15) x 1KB = 32 KB
  __shared__ __align__(16) unsigned short tiles[2][16 * 512];

  constexpr int SPL = SEQ / NS;
  constexpr int NT  = SPL / KVB;
  constexpr int NWG = 4 * NS * 16;
  constexpr int CPX = NWG / 8;

  const int raw = blockIdx.x;
  const int bid = (raw & 7) * CPX + (raw >> 3);   // XCD-contiguous, bijective
  const int b     = bid / (NS * 16);
  const int rem   = bid % (NS * 16);
  const int split = rem >> 4;
  const int qblk  = rem & 15;

  const int tid  = threadIdx.x;
  const int wave = tid >> 6;
  const int lane = tid & 63;
  const int l5   = lane & 31;
  const int b5   = lane >> 5;

  const int qrow0 = qblk * 256 + wave * 64;
  const int kv0   = split * SPL;

  // ---- Q fragments, two groups: rows qrow0 + g*32 + l5 ---------------------
  u16x8 qa[4], qb[4];
  #pragma unroll
  for (int g = 0; g < 2; ++g) {
    const float* qp = Q + ((long)b * SEQ + qrow0 + g * 32 + l5) * DIM;
    #pragma unroll
    for (int ch = 0; ch < 4; ++ch) {
      const float* p = qp + ch * 16 + b5 * 8;
      float4 x0 = *(const float4*)(p);
      float4 x1 = *(const float4*)(p + 4);
      u32x4 qw = {cvtpk(x0.x * QSCALE, x0.y * QSCALE),
                  cvtpk(x0.z * QSCALE, x0.w * QSCALE),
                  cvtpk(x1.x * QSCALE, x1.y * QSCALE),
                  cvtpk(x1.z * QSCALE, x1.w * QSCALE)};
      if (g == 0) qa[ch] = __builtin_bit_cast(u16x8, qw);
      else        qb[ch] = __builtin_bit_cast(u16x8, qw);
    }
  }

  // ---- staging roles (identical to R10) ------------------------------------
  const int kvrole = wave >> 1;            // 0: K blocks 0-7, 1: V blocks 8-15
  const int lb     = (wave & 1) * 4;
  const unsigned short* gsrc =
      kvrole ? Vf + (((long)b * 64 + (kv0 >> 6)) * 8) * 512
             : Kf + (((long)b * 128 + (kv0 >> 5)) * 4) * 512;

  auto stage = [&](int buf, int t) {
    const unsigned short* s = gsrc + (long)t * 4096 + lb * 512 + lane * 8;
    unsigned short* d = &tiles[buf][(kvrole * 8 + lb) * 512];
    #pragma unroll
    for (int i = 0; i < 4; ++i)
      __builtin_amdgcn_global_load_lds(
          (__attribute__((address_space(1))) void*)(s + i * 512),
          (__attribute__((address_space(3))) void*)(d + i * 512), 16, 0, 0);
  };

  stage(0, 0);
  __syncthreads();

  f32x16 OA0 = {0,0,0,0,0,0,0,0,0,0,0,0,0,0,0,0};   // g0, d 0-31
  f32x16 OA1 = {0,0,0,0,0,0,0,0,0,0,0,0,0,0,0,0};   // g0, d 32-63
  f32x16 OB0 = {0,0,0,0,0,0,0,0,0,0,0,0,0,0,0,0};   // g1, d 0-31
  f32x16 OB1 = {0,0,0,0,0,0,0,0,0,0,0,0,0,0,0,0};   // g1, d 32-63
  float lsA = 0.0f, lsB = 0.0f;

  for (int t = 0; t < NT; ++t) {
    const int buf = t & 1;
    if (t + 1 < NT) stage(buf ^ 1, t + 1);

    const u16x8* fb = (const u16x8*)(&tiles[buf][0]) + lane;

    // ---- fragments read ONCE per wave, reused by both q-groups ------------
    u16x8 kf0 = fb[0*64], kf1 = fb[1*64], kf2 = fb[2*64], kf3 = fb[3*64];
    u16x8 kf4 = fb[4*64], kf5 = fb[5*64], kf6 = fb[6*64], kf7 = fb[7*64];
    u16x8 vf0 = fb[ 8*64], vf1 = fb[ 9*64], vf2 = fb[10*64], vf3 = fb[11*64];
    u16x8 vf4 = fb[12*64], vf5 = fb[13*64], vf6 = fb[14*64], vf7 = fb[15*64];

    // ==== group 0 ==========================================================
    {
      f32x16 s0 = {0,0,0,0,0,0,0,0,0,0,0,0,0,0,0,0};
      f32x16 s1 = {0,0,0,0,0,0,0,0,0,0,0,0,0,0,0,0};
      __builtin_amdgcn_s_setprio(1);
      s0 = MFMA32(kf0, qa[0], s0);  s1 = MFMA32(kf4, qa[0], s1);
      s0 = MFMA32(kf1, qa[1], s0);  s1 = MFMA32(kf5, qa[1], s1);
      s0 = MFMA32(kf2, qa[2], s0);  s1 = MFMA32(kf6, qa[2], s1);
      s0 = MFMA32(kf3, qa[3], s0);  s1 = MFMA32(kf7, qa[3], s1);
      __builtin_amdgcn_s_setprio(0);

      #pragma unroll
      for (int hf = 0; hf < 2; ++hf) {
        const f32x16& sc = hf ? s1 : s0;
        float p[16];
        #pragma unroll
        for (int r = 0; r < 16; ++r) p[r] = EXP2F(sc[r]);
        float u[8];
        #pragma unroll
        for (int r = 0; r < 8; ++r) u[r] = p[r] + p[r + 8];
        #pragma unroll
        for (int r = 0; r < 4; ++r) u[r] += u[r + 4];
        lsA += (u[0] + u[1]) + (u[2] + u[3]);

        unsigned int a0 = cvtpk(p[0], p[1]),   a1 = cvtpk(p[2], p[3]);
        unsigned int a2 = cvtpk(p[4], p[5]),   a3 = cvtpk(p[6], p[7]);
        unsigned int c0 = cvtpk(p[8], p[9]),   c1 = cvtpk(p[10], p[11]);
        unsigned int c2 = cvtpk(p[12], p[13]), c3 = cvtpk(p[14], p[15]);
        plswap(a0, a2); plswap(a1, a3);
        plswap(c0, c2); plswap(c1, c3);
        u32x4 w0 = {a0, a1, a2, a3};
        u32x4 w1 = {c0, c1, c2, c3};
        u16x8 pbA = __builtin_bit_cast(u16x8, w0);   // keys hf*32 + 0-15
        u16x8 pbB = __builtin_bit_cast(u16x8, w1);   // keys hf*32 + 16-31

        const u16x8& vA0 = hf ? vf2 : vf0;           // dh0, ks = hf*2
        const u16x8& vA1 = hf ? vf3 : vf1;           // dh0, ks = hf*2+1
        const u16x8& vB0 = hf ? vf6 : vf4;           // dh1
        const u16x8& vB1 = hf ? vf7 : vf5;

        __builtin_amdgcn_s_setprio(1);
        OA0 = MFMA32(vA0, pbA, OA0);  OA1 = MFMA32(vB0, pbA, OA1);
        OA0 = MFMA32(vA1, pbB, OA0);  OA1 = MFMA32(vB1, pbB, OA1);
        __builtin_amdgcn_s_setprio(0);
      }
    }

    // ==== group 1 ==========================================================
    {
      f32x16 s0 = {0,0,0,0,0,0,0,0,0,0,0,0,0,0,0,0};
      f32x16 s1 = {0,0,0,0,0,0,0,0,0,0,0,0,0,0,0,0};
      __builtin_amdgcn_s_setprio(1);
      s0 = MFMA32(kf0, qb[0], s0);  s1 = MFMA32(kf4, qb[0], s1);
      s0 = MFMA32(kf1, qb[1], s0);  s1 = MFMA32(kf5, qb[1], s1);
      s0 = MFMA32(kf2, qb[2], s0);  s1 = MFMA32(kf6, qb[2], s1);
      s0 = MFMA32(kf3, qb[3], s0);  s1 = MFMA32(kf7, qb[3], s1);
      __builtin_amdgcn_s_setprio(0);

      #pragma unroll
      for (int hf = 0; hf < 2; ++hf) {
        const f32x16& sc = hf ? s1 : s0;
        float p[16];
        #pragma unroll
        for (int r = 0; r < 16; ++r) p[r] = EXP2F(sc[r]);
        float u[8];
        #pragma unroll
        for (int r = 0; r < 8; ++r) u[r] = p[r] + p[r + 8];
        #pragma unroll
        for (int r = 0; r < 4; ++r) u[r] += u[r + 4];
        lsB += (u[0] + u[1]) + (u[2] + u[3]);

        unsigned int a0 = cvtpk(p[0], p[1]),   a1 = cvtpk(p[2], p[3]);
        unsigned int a2 = cvtpk(p[4], p[5]),   a3 = cvtpk(p[6], p[7]);
        unsigned int c0 = cvtpk(p[8], p[9]),   c1 = cvtpk(p[10], p[11]);
        unsigned int c2 = cvtpk(p[12], p[13]), c3 = cvtpk(p[14], p[15]);
        plswap(a0, a2); plswap(a1, a3);
        plswap(c0, c2); plswap(c1, c3);
        u32x4 w0 = {a0, a1, a2, a3};
        u32x4 w1 = {c0, c1, c2, c3};
        u16x8 pbA = __builtin_bit_cast(u16x8, w0);
        u16x8 pbB = __builtin_bit_cast(u16x8, w1);

        const u16x8& vA0 = hf ? vf2 : vf0;
        const u16x8& vA1 = hf ? vf3 : vf1;
        const u16x8& vB0 = hf ? vf6 : vf4;
        const u16x8& vB1 = hf ? vf7 : vf5;

        __builtin_amdgcn_s_setprio(1);
        OB0 = MFMA32(vA0, pbA, OB0);  OB1 = MFMA32(vB0, pbA, OB1);
        OB0 = MFMA32(vA1, pbB, OB0);  OB1 = MFMA32(vB1, pbB, OB1);
        __builtin_amdgcn_s_setprio(0);
      }
    }

    __syncthreads();
  }

  // ---- combine lane-local sums across lane^32 ------------------------------
  lsA = xsum32(lsA);
  lsB = xsum32(lsB);

  // ---- fp32 raw-dump epilogue (R10 layout + g bit) -------------------------
  // block k = g*2+mt at ((bid*4+wave)*4+k)*1024 + lane*16 + r
  {
    float* ob = Opart + ((long)(bid * 4 + wave) * 4) * 1024 + lane * 16;
    #pragma unroll
    for (int k = 0; k < 4; ++k) {
      const f32x16& A = (k == 0) ? OA0 : (k == 1) ? OA1 : (k == 2) ? OB0 : OB1;
      *(float4*)(ob + k * 1024 +  0) = float4{A[0],  A[1],  A[2],  A[3]};
      *(float4*)(ob + k * 1024 +  4) = float4{A[4],  A[5],  A[6],  A[7]};
      *(float4*)(ob + k * 1024 +  8) = float4{A[8],  A[9],  A[10], A[11]};
      *(float4*)(ob + k * 1024 + 12) = float4{A[12], A[13], A[14], A[15]};
    }
  }
  {
    const int g = b5;                       // lanes<32 write g0, >=32 write g1
    const float ls = g ? lsB : lsA;
    long qg = (long)b * SEQ + qrow0 + g * 32 + l5;
    Lpart[(long)split * NQ + qg] = ls;
  }
}

// ---------------- merge: plain sum of fp32 partials, normalize --------------
template<int NS>
__global__ __launch_bounds__(256) void merge_kernel(
    const float* __restrict__ Opart, const float* __restrict__ Lpart,
    float* __restrict__ Out) {
  int idx = blockIdx.x * 256 + threadIdx.x;  // over NQ*16
  int bq = idx >> 4;
  int d4 = (idx & 15) << 2;
  // inverse of the raw-dump layout
  int b    = bq >> 12;
  int qm   = bq & 4095;
  int qblk = qm >> 8;
  int win  = qm & 255;
  int wv   = win >> 6;
  int qw   = win & 63;
  int g    = qw >> 5;
  int l5   = qw & 31;
  int mt   = d4 >> 5;
  int d5   = d4 & 31;
  int b5v  = (d5 >> 2) & 1;
  int g4   = d5 >> 3;
  int lane = b5v * 32 + l5;

  float4 acc = {0, 0, 0, 0};
  float L = 0.0f;
  #pragma unroll
  for (int s = 0; s < NS; ++s) {
    long bidl = ((long)b * NS + s) * 16 + qblk;
    long off = ((bidl * 4 + wv) * 4 + g * 2 + mt) * 1024 + lane * 16 + g4 * 4;
    float4 o = *(const float4*)(Opart + off);
    acc.x += o.x; acc.y += o.y; acc.z += o.z; acc.w += o.w;
    L += Lpart[(long)s * NQ + bq];
  }
  float inv = 1.0f / L;
  *(float4*)(Out + (long)bq * DIM + d4) =
      float4{acc.x * inv, acc.y * inv, acc.z * inv, acc.w * inv};
}

extern "C" void kernel_launch(void* const* d_in, const int* in_sizes, int n_in,
                              void* d_out, int out_size, void* d_ws, size_t ws_size,
                              hipStream_t stream) {
  const float* Q = (const float*)d_in[0];
  const float* K = (const float*)d_in[1];
  const float* V = (const float*)d_in[2];
  float* Out = (float*)d_out;

  // ws: [Kf|Vf] bf16 fragment-ordered (4 MB) + Opart fp32 (NS*4MB) + Lpart
  unsigned short* w16 = (unsigned short*)d_ws;
  unsigned short* Kf  = w16;
  unsigned short* Vf  = w16 + 1048576;
  float* wsf = (float*)(w16 + 2097152);

  const size_t need8 = (size_t)4 * 1024 * 1024 + (size_t)8 * NQ * DIM * 4
                     + (size_t)8 * NQ * 4;
  const int ns = (ws_size >= need8) ? 8 : 4;

  prep_kernel<<<dim3(256), dim3(256), 0, stream>>>(K, V, Kf, Vf);
  if (ns == 8) {
    float* Opart = wsf;
    float* Lpart = wsf + (size_t)8 * NQ * DIM;
    attn_kernel<8><<<dim3(512), dim3(256), 0, stream>>>(Q, Kf, Vf, Opart, Lpart);
    merge_kernel<8><<<dim3(1024), dim3(256), 0, stream>>>(Opart, Lpart, Out);
  } else {
    float* Opart = wsf;
    float* Lpart = wsf + (size_t)4 * NQ * DIM;
    attn_kernel<4><<<dim3(256), dim3(256), 0, stream>>>(Q, Kf, Vf, Opart, Lpart);
    merge_kernel<4><<<dim3(1024), dim3(256), 0, stream>>>(Opart, Lpart, Out);
  }
}

// Round 14
// 40.424 us; speedup vs baseline: 1.2931x; 1.2931x over previous
//
#include <hip/hip_runtime.h>

// AttentionHead: B=4, S=4096, D=64, fp32 in/out.
// R14 = R10 (verified 44.7us structure, untouched) + bf16 Opart partials
// using ONLY in-house verified primitives: pack = cvtpk (v_cvt_pk_bf16_f32,
// proven in the P-path since R2; low=arg0), unpack = <<16 / &0xffff0000
// (proven since R0). No hip_fp16 intrinsics (R11/R13's identical-absmax
// failures localize there). Halves epilogue writes + merge reads.

#define BATCH 4
#define SEQ   4096
#define DIM   64
#define KVB   64
#define NQ    16384                  // BATCH*SEQ
#define QSCALE 0.18033688011112042f  // (1/sqrt(64)) * log2(e); all exps are exp2

typedef float f32x16 __attribute__((ext_vector_type(16)));
typedef unsigned short u16x8 __attribute__((ext_vector_type(8)));
typedef unsigned int   u32x4 __attribute__((ext_vector_type(4)));
typedef unsigned int   u32x2 __attribute__((ext_vector_type(2)));

#define MFMA32(a, b, c) __builtin_amdgcn_mfma_f32_32x32x16_bf16((a), (b), (c), 0, 0, 0)
#define EXP2F(x) __builtin_amdgcn_exp2f(x)

__device__ __forceinline__ void plswap(unsigned int& a, unsigned int& b) {
  u32x2 r = __builtin_amdgcn_permlane32_swap(a, b, false, false);
  a = r[0]; b = r[1];
}
__device__ __forceinline__ float xsum32(float x) {   // total across lane^32
  unsigned int u = __float_as_uint(x), v = u;
  plswap(u, v);
  return __uint_as_float(u) + __uint_as_float(v);
}

__device__ __forceinline__ unsigned short f2bf(float x) {
  unsigned int u = __float_as_uint(x);
  return (unsigned short)((u + 0x7fffu + ((u >> 16) & 1u)) >> 16);   // RNE
}
__device__ __forceinline__ unsigned int cvtpk(float a, float b) {  // lo=a, hi=b
  unsigned int r;
  asm("v_cvt_pk_bf16_f32 %0, %1, %2" : "=v"(r) : "v"(a), "v"(b));
  return r;
}
__device__ __forceinline__ float bflo(unsigned int w) { return __uint_as_float(w << 16); }
__device__ __forceinline__ float bfhi(unsigned int w) { return __uint_as_float(w & 0xffff0000u); }

// ---------------- prep: K,V -> fragment-ordered bf16 (verified R7-R12) ------
// Kf block (b, kb32, ch): elem l*8+j = K[b][kb32*32+(l&31)][ch*16+(l>>5)*8+j]
// Vf block (b, kb64, dh, ks): elem l*8+j = V[b][kb64*64+ks*16+(l>>5)*8+j][dh*32+(l&31)]
__global__ __launch_bounds__(256) void prep_kernel(
    const float* __restrict__ K, const float* __restrict__ V,
    unsigned short* __restrict__ Kf, unsigned short* __restrict__ Vf) {
  __shared__ float tk[64][65];
  __shared__ float tv[64][65];
  const int t = threadIdx.x;
  const int b = blockIdx.x >> 6;
  const int s0 = (blockIdx.x & 63) << 6;
  #pragma unroll
  for (int r = 0; r < 4; ++r) {
    const int s_loc = r * 16 + (t >> 4);
    const int d0 = (t & 15) << 2;
    const long base = ((long)b * SEQ + s0 + s_loc) * DIM + d0;
    const float4 kv = *(const float4*)(K + base);
    const float4 vv = *(const float4*)(V + base);
    tk[s_loc][d0 + 0] = kv.x; tk[s_loc][d0 + 1] = kv.y;
    tk[s_loc][d0 + 2] = kv.z; tk[s_loc][d0 + 3] = kv.w;
    tv[s_loc][d0 + 0] = vv.x; tv[s_loc][d0 + 1] = vv.y;
    tv[s_loc][d0 + 2] = vv.z; tv[s_loc][d0 + 3] = vv.w;
  }
  __syncthreads();
  const int l  = t >> 2;           // 0..63 (fragment lane)
  const int j0 = (t & 3) << 1;     // 0,2,4,6
  const int l5 = l & 31, b5 = l >> 5;
  #pragma unroll
  for (int kh = 0; kh < 2; ++kh) {
    #pragma unroll
    for (int ch = 0; ch < 4; ++ch) {
      const int key = kh * 32 + l5;
      const int d   = ch * 16 + b5 * 8 + j0;
      ushort2 w;
      w.x = f2bf(tk[key][d]);
      w.y = f2bf(tk[key][d + 1]);
      const long kb32 = (s0 >> 5) + kh;
      const long off = (((long)b * 128 + kb32) * 4 + ch) * 512 + 2 * t;
      *(ushort2*)(Kf + off) = w;
    }
  }
  #pragma unroll
  for (int dh = 0; dh < 2; ++dh) {
    #pragma unroll
    for (int ks = 0; ks < 4; ++ks) {
      const int key0 = ks * 16 + b5 * 8 + j0;
      const int d    = dh * 32 + l5;
      ushort2 w;
      w.x = f2bf(tv[key0][d]);
      w.y = f2bf(tv[key0 + 1][d]);
      const long kb64 = (s0 >> 6);
      const long off = ((((long)b * 64 + kb64) * 2 + dh) * 4 + ks) * 512 + 2 * t;
      *(ushort2*)(Vf + off) = w;
    }
  }
}

// ---------------- attention main kernel (R10 structure, verbatim) -----------
template<int NS>
__global__ __launch_bounds__(256, 4) void attn_kernel(
    const float* __restrict__ Q,
    const unsigned short* __restrict__ Kf, const unsigned short* __restrict__ Vf,
    unsigned int* __restrict__ Opart, float* __restrict__ Lpart) {

  // 2 bufs x 16 fragment blocks (K: 0-7, V: 8-15) x 1KB = 32 KB
  __shared__ __align__(16) unsigned short tiles[2][16 * 512];

  constexpr int SPL = SEQ / NS;
  constexpr int NT  = SPL / KVB;
  constexpr int NWG = 4 * NS * 32;
  constexpr int CPX = NWG / 8;

  const int raw = blockIdx.x;
  const int bid = (raw & 7) * CPX + (raw >> 3);   // XCD-contiguous, bijective
  const int b     = bid / (NS * 32);
  const int rem   = bid % (NS * 32);
  const int split = rem >> 5;
  const int qblk  = rem & 31;

  const int tid  = threadIdx.x;
  const int wave = tid >> 6;
  const int lane = tid & 63;
  const int l5   = lane & 31;
  const int b5   = lane >> 5;

  const int qrow0 = qblk * 128 + wave * 32;
  const int kv0   = split * SPL;

  // ---- Q fragments ---------------------------------------------------------
  u16x8 qh[4];
  {
    const float* qp = Q + ((long)b * SEQ + qrow0 + l5) * DIM;
    #pragma unroll
    for (int ch = 0; ch < 4; ++ch) {
      const float* p = qp + ch * 16 + b5 * 8;
      float4 x0 = *(const float4*)(p);
      float4 x1 = *(const float4*)(p + 4);
      u32x4 qw = {cvtpk(x0.x * QSCALE, x0.y * QSCALE),
                  cvtpk(x0.z * QSCALE, x0.w * QSCALE),
                  cvtpk(x1.x * QSCALE, x1.y * QSCALE),
                  cvtpk(x1.z * QSCALE, x1.w * QSCALE)};
      qh[ch] = __builtin_bit_cast(u16x8, qw);
    }
  }

  // ---- staging roles -------------------------------------------------------
  const int kvrole = wave >> 1;            // 0: K blocks 0-7, 1: V blocks 8-15
  const int lb     = (wave & 1) * 4;
  const unsigned short* gsrc =
      kvrole ? Vf + (((long)b * 64 + (kv0 >> 6)) * 8) * 512
             : Kf + (((long)b * 128 + (kv0 >> 5)) * 4) * 512;

  auto stage = [&](int buf, int t) {
    const unsigned short* s = gsrc + (long)t * 4096 + lb * 512 + lane * 8;
    unsigned short* d = &tiles[buf][(kvrole * 8 + lb) * 512];
    #pragma unroll
    for (int i = 0; i < 4; ++i)
      __builtin_amdgcn_global_load_lds(
          (__attribute__((address_space(1))) void*)(s + i * 512),
          (__attribute__((address_space(3))) void*)(d + i * 512), 16, 0, 0);
  };

  stage(0, 0);
  __syncthreads();

  f32x16 O0 = {0,0,0,0,0,0,0,0,0,0,0,0,0,0,0,0};
  f32x16 O1 = {0,0,0,0,0,0,0,0,0,0,0,0,0,0,0,0};
  float lsum = 0.0f;

  for (int t = 0; t < NT; ++t) {
    const int buf = t & 1;
    if (t + 1 < NT) stage(buf ^ 1, t + 1);

    const u16x8* fb = (const u16x8*)(&tiles[buf][0]) + lane;

    // ---- QK^T swapped, both 32-key halves ---------------------------------
    f32x16 sc0 = {0,0,0,0,0,0,0,0,0,0,0,0,0,0,0,0};
    f32x16 sc1 = {0,0,0,0,0,0,0,0,0,0,0,0,0,0,0,0};
    __builtin_amdgcn_s_setprio(1);
    sc0 = MFMA32(fb[0 * 64], qh[0], sc0);  sc1 = MFMA32(fb[4 * 64], qh[0], sc1);
    sc0 = MFMA32(fb[1 * 64], qh[1], sc0);  sc1 = MFMA32(fb[5 * 64], qh[1], sc1);
    sc0 = MFMA32(fb[2 * 64], qh[2], sc0);  sc1 = MFMA32(fb[6 * 64], qh[2], sc1);
    sc0 = MFMA32(fb[3 * 64], qh[3], sc0);  sc1 = MFMA32(fb[7 * 64], qh[3], sc1);
    __builtin_amdgcn_s_setprio(0);

    // ---- half 0: exp -> sum -> pack -> PV ---------------------------------
    {
      float p[16];
      #pragma unroll
      for (int r = 0; r < 16; ++r) p[r] = EXP2F(sc0[r]);
      float u[8];
      #pragma unroll
      for (int r = 0; r < 8; ++r) u[r] = p[r] + p[r + 8];
      #pragma unroll
      for (int r = 0; r < 4; ++r) u[r] += u[r + 4];
      lsum += (u[0] + u[1]) + (u[2] + u[3]);

      unsigned int a0 = cvtpk(p[0], p[1]),   a1 = cvtpk(p[2], p[3]);
      unsigned int a2 = cvtpk(p[4], p[5]),   a3 = cvtpk(p[6], p[7]);
      unsigned int c0 = cvtpk(p[8], p[9]),   c1 = cvtpk(p[10], p[11]);
      unsigned int c2 = cvtpk(p[12], p[13]), c3 = cvtpk(p[14], p[15]);
      plswap(a0, a2); plswap(a1, a3);
      plswap(c0, c2); plswap(c1, c3);
      u32x4 w0 = {a0, a1, a2, a3};          // keys 0-15  (ks0)
      u32x4 w1 = {c0, c1, c2, c3};          // keys 16-31 (ks1)
      u16x8 pb0 = __builtin_bit_cast(u16x8, w0);
      u16x8 pb1 = __builtin_bit_cast(u16x8, w1);

      __builtin_amdgcn_s_setprio(1);
      O0 = MFMA32(fb[ 8 * 64], pb0, O0);  O1 = MFMA32(fb[12 * 64], pb0, O1);
      O0 = MFMA32(fb[ 9 * 64], pb1, O0);  O1 = MFMA32(fb[13 * 64], pb1, O1);
      __builtin_amdgcn_s_setprio(0);
    }

    // ---- half 1 ------------------------------------------------------------
    {
      float p[16];
      #pragma unroll
      for (int r = 0; r < 16; ++r) p[r] = EXP2F(sc1[r]);
      float u[8];
      #pragma unroll
      for (int r = 0; r < 8; ++r) u[r] = p[r] + p[r + 8];
      #pragma unroll
      for (int r = 0; r < 4; ++r) u[r] += u[r + 4];
      lsum += (u[0] + u[1]) + (u[2] + u[3]);

      unsigned int a0 = cvtpk(p[0], p[1]),   a1 = cvtpk(p[2], p[3]);
      unsigned int a2 = cvtpk(p[4], p[5]),   a3 = cvtpk(p[6], p[7]);
      unsigned int c0 = cvtpk(p[8], p[9]),   c1 = cvtpk(p[10], p[11]);
      unsigned int c2 = cvtpk(p[12], p[13]), c3 = cvtpk(p[14], p[15]);
      plswap(a0, a2); plswap(a1, a3);
      plswap(c0, c2); plswap(c1, c3);
      u32x4 w0 = {a0, a1, a2, a3};          // keys 32-47 (ks2)
      u32x4 w1 = {c0, c1, c2, c3};          // keys 48-63 (ks3)
      u16x8 pb2 = __builtin_bit_cast(u16x8, w0);
      u16x8 pb3 = __builtin_bit_cast(u16x8, w1);

      __builtin_amdgcn_s_setprio(1);
      O0 = MFMA32(fb[10 * 64], pb2, O0);  O1 = MFMA32(fb[14 * 64], pb2, O1);
      O0 = MFMA32(fb[11 * 64], pb3, O0);  O1 = MFMA32(fb[15 * 64], pb3, O1);
      __builtin_amdgcn_s_setprio(0);
    }

    __syncthreads();
  }

  // ---- combine lane-local lsum across the lane^32 split -------------------
  lsum = xsum32(lsum);

  // ---- bf16 raw-dump epilogue (R10 layout, units halved; word w = ---------
  //      (A[2w] lo, A[2w+1] hi) via verified cvtpk) -------------------------
  unsigned int* ob = Opart + (long)split * (NQ * DIM / 2)
                   + ((long)((b * 32 + qblk) * 4 + wave) * 2) * 512 + lane * 8;
  {
    u32x4 lo0 = {cvtpk(O0[0],  O0[1]),  cvtpk(O0[2],  O0[3]),
                 cvtpk(O0[4],  O0[5]),  cvtpk(O0[6],  O0[7])};
    u32x4 hi0 = {cvtpk(O0[8],  O0[9]),  cvtpk(O0[10], O0[11]),
                 cvtpk(O0[12], O0[13]), cvtpk(O0[14], O0[15])};
    u32x4 lo1 = {cvtpk(O1[0],  O1[1]),  cvtpk(O1[2],  O1[3]),
                 cvtpk(O1[4],  O1[5]),  cvtpk(O1[6],  O1[7])};
    u32x4 hi1 = {cvtpk(O1[8],  O1[9]),  cvtpk(O1[10], O1[11]),
                 cvtpk(O1[12], O1[13]), cvtpk(O1[14], O1[15])};
    *(u32x4*)(ob + 0)       = lo0;
    *(u32x4*)(ob + 4)       = hi0;
    *(u32x4*)(ob + 512 + 0) = lo1;
    *(u32x4*)(ob + 512 + 4) = hi1;
  }
  if (lane < 32) {
    long qg = (long)b * SEQ + qrow0 + lane;
    Lpart[(long)split * NQ + qg] = lsum;
  }
}

// ---------------- merge: plain sum of bf16 partials, normalize --------------
template<int NS>
__global__ __launch_bounds__(256) void merge_kernel(
    const unsigned int* __restrict__ Opart, const float* __restrict__ Lpart,
    float* __restrict__ Out) {
  int idx = blockIdx.x * 256 + threadIdx.x;  // over NQ*16
  int bq = idx >> 4;
  int d4 = (idx & 15) << 2;
  // inverse of the raw-dump layout (R10-verified decomposition)
  int b    = bq >> 12;
  int qrow = bq & 4095;
  int qblk = qrow >> 7;
  int wv   = (qrow >> 5) & 3;
  int l5   = qrow & 31;
  int mt   = d4 >> 5;
  int d5   = d4 & 31;
  int b5v  = (d5 >> 2) & 1;
  int g    = d5 >> 3;
  int lane = b5v * 32 + l5;
  long off0 = ((long)((b * 32 + qblk) * 4 + wv) * 2 + mt) * 512 + lane * 8 + g * 2;

  float4 acc = {0, 0, 0, 0};
  float L = 0.0f;
  #pragma unroll
  for (int s = 0; s < NS; ++s) {
    u32x2 pr = *(const u32x2*)(Opart + (long)s * (NQ * DIM / 2) + off0);
    acc.x += bflo(pr[0]); acc.y += bfhi(pr[0]);
    acc.z += bflo(pr[1]); acc.w += bfhi(pr[1]);
    L += Lpart[(long)s * NQ + bq];
  }
  float inv = 1.0f / L;
  *(float4*)(Out + (long)bq * DIM + d4) =
      float4{acc.x * inv, acc.y * inv, acc.z * inv, acc.w * inv};
}

extern "C" void kernel_launch(void* const* d_in, const int* in_sizes, int n_in,
                              void* d_out, int out_size, void* d_ws, size_t ws_size,
                              hipStream_t stream) {
  const float* Q = (const float*)d_in[0];
  const float* K = (const float*)d_in[1];
  const float* V = (const float*)d_in[2];
  float* Out = (float*)d_out;

  // ws: [Kf|Vf] bf16 fragment-ordered (4 MB) + Opart bf16 (NS*2MB) + Lpart
  unsigned short* w16 = (unsigned short*)d_ws;
  unsigned short* Kf  = w16;
  unsigned short* Vf  = w16 + 1048576;
  unsigned int* Opart = (unsigned int*)(w16 + 2097152);

  const size_t need8 = (size_t)4 * 1024 * 1024 + (size_t)8 * NQ * DIM * 2
                     + (size_t)8 * NQ * 4;
  const int ns = (ws_size >= need8) ? 8 : 4;

  prep_kernel<<<dim3(256), dim3(256), 0, stream>>>(K, V, Kf, Vf);
  if (ns == 8) {
    float* Lpart = (float*)(Opart + (size_t)8 * NQ * DIM / 2);
    attn_kernel<8><<<dim3(1024), dim3(256), 0, stream>>>(Q, Kf, Vf, Opart, Lpart);
    merge_kernel<8><<<dim3(1024), dim3(256), 0, stream>>>(Opart, Lpart, Out);
  } else {
    float* Lpart = (float*)(Opart + (size_t)4 * NQ * DIM / 2);
    attn_kernel<4><<<dim3(512), dim3(256), 0, stream>>>(Q, Kf, Vf, Opart, Lpart);
    merge_kernel<4><<<dim3(1024), dim3(256), 0, stream>>>(Opart, Lpart, Out);
  }
}